// Round 12
// baseline (176.688 us; speedup 1.0000x reference)
//
#include <hip/hip_runtime.h>

#define DM 1024
#define NH 16
#define TT 2048
#define BB 2
#define NTOK (BB*TT)
#define DQKV 3072

typedef __attribute__((ext_vector_type(8))) short bf16x8;   // 8 bf16 (4 VGPRs)
typedef __attribute__((ext_vector_type(4))) float f32x4;    // MFMA C/D
typedef __attribute__((ext_vector_type(4))) int  int4v;     // 16B chunk

static __device__ __forceinline__ short f2b(float f) {
  union { float f; unsigned u; } v; v.f = f;
  unsigned r = v.u + 0x7FFFu + ((v.u >> 16) & 1u);   // RNE fp32->bf16
  return (short)(r >> 16);
}

// ---------------- fp32 -> bf16 convert (x) ----------------
__global__ __launch_bounds__(256) void k_convert(const float* __restrict__ in,
                                                 short* __restrict__ out, int n) {
  int i = (blockIdx.x * 256 + threadIdx.x) * 8;
  if (i >= n) return;
  float4 a = *(const float4*)(in + i);
  float4 b = *(const float4*)(in + i + 4);
  bf16x8 o;
  o[0]=f2b(a.x); o[1]=f2b(a.y); o[2]=f2b(a.z); o[3]=f2b(a.w);
  o[4]=f2b(b.x); o[5]=f2b(b.y); o[6]=f2b(b.z); o[7]=f2b(b.w);
  *(bf16x8*)(out + i) = o;
}

// ---------------- all 4 weights [K][N] fp32 -> [N][K] bf16, one launch ----------------
__global__ __launch_bounds__(256) void k_transpose_w4(const float* __restrict__ Wq,
                                                      const float* __restrict__ Wk,
                                                      const float* __restrict__ Wv,
                                                      const float* __restrict__ Wo,
                                                      short* __restrict__ WqkvT,
                                                      short* __restrict__ WoT) {
  __shared__ short t[64][72];
  const int z = blockIdx.z;
  const float* W = (z == 0) ? Wq : (z == 1) ? Wk : (z == 2) ? Wv : Wo;
  short* Wt = (z < 3) ? WqkvT : WoT;
  const int row0 = (z < 3) ? z * 1024 : 0;
  int tid = threadIdx.x;
  int n0 = blockIdx.x * 64, k0 = blockIdx.y * 64;
  #pragma unroll
  for (int i = 0; i < 4; i++) {
    int id = tid + 256 * i;
    int r = id >> 4;        // k row within tile
    int c = id & 15;        // float4 chunk along n
    float4 v = *(const float4*)(W + (size_t)(k0 + r) * DM + n0 + c * 4);
    t[c*4+0][r] = f2b(v.x);
    t[c*4+1][r] = f2b(v.y);
    t[c*4+2][r] = f2b(v.z);
    t[c*4+3][r] = f2b(v.w);
  }
  __syncthreads();
  #pragma unroll
  for (int i = 0; i < 2; i++) {
    int id = tid + 256 * i;
    int r = id >> 3;        // n row
    int c = id & 7;         // 8-elem chunk along k
    bf16x8 o = *(const bf16x8*)&t[r][c * 8];
    *(bf16x8*)(Wt + (size_t)(row0 + n0 + r) * DM + k0 + c * 8) = o;
  }
}

// ---------------- V (cols of Qkv) -> Vt [BB*NH][64][TT] bf16 ----------------
__global__ __launch_bounds__(256) void k_transpose_v(const short* __restrict__ V,
                                                     short* __restrict__ Vt) {
  __shared__ short t[64][72];
  int tid = threadIdx.x;
  int bh = blockIdx.y;
  int b = bh >> 4, h = bh & 15;
  int t0 = blockIdx.x * 64;
  #pragma unroll
  for (int i = 0; i < 2; i++) {
    int id = tid + 256 * i;
    int r = id >> 3;        // t row
    int c = id & 7;         // 8-bf16 chunk along d
    bf16x8 v = *(const bf16x8*)(V + (size_t)(b * TT + t0 + r) * DQKV + h * 64 + c * 8);
    #pragma unroll
    for (int e = 0; e < 8; e++) t[c * 8 + e][r] = v[e];
  }
  __syncthreads();
  #pragma unroll
  for (int i = 0; i < 2; i++) {
    int id = tid + 256 * i;
    int r = id >> 3;        // d row
    int c = id & 7;         // t chunk
    bf16x8 o = *(const bf16x8*)&t[r][c * 8];
    *(bf16x8*)(Vt + (size_t)(bh * 64 + r) * TT + t0 + c * 8) = o;
  }
}

// ---------------- GEMM NT: C[M][N] = A[M][K] * Bt[N][K]^T ----------------
// r10 version: 2-phase double-buffered, global_load_lds staging, G21 involution
// swizzle, T1 XCD-chunked bijective remap, __syncthreads sync (T4 reverted —
// counted vmcnt regressed on this 2-barrier structure, r11).
template<int OUT_BF16, int BN>
__global__ __launch_bounds__(256) void k_gemm_lds(const short* __restrict__ A,
                                                  const short* __restrict__ Bt,
                                                  void* __restrict__ C,
                                                  int M, int N, int K,
                                                  int qcols, float qscale) {
  __shared__ short As[2][128 * 64];
  __shared__ short Bs[2][BN * 64];
  constexpr int NI = BN / 32;               // 16-wide n-frags per wave
  const int tid = threadIdx.x;
  const int lane = tid & 63, w = tid >> 6;
  const int wm = w >> 1, wn = w & 1;        // 2x2 wave grid
  const int l15 = lane & 15, g = lane >> 4;
  const int nx = N / BN;
  const int cx = nx >> 3;
  const int bid = blockIdx.x;
  const int xcd = bid & 7, k_ = bid >> 3;
  const int bx = xcd * cx + (k_ % cx), by = k_ / cx;
  const int m0 = by * 128, n0 = bx * BN;
  const int srow = lane >> 3;               // 0..7 row within 8-row segment
  const int scol = ((lane & 7) ^ srow) * 8; // pre-swizzled SOURCE chunk (shorts)
  const int rsw = l15 & 7;                  // read-side XOR (row&7 == l15&7)

  auto stage = [&](int buf, int k0) {
    #pragma unroll
    for (int i = 0; i < 4; i++) {
      int rbase = w * 32 + i * 8;
      __builtin_amdgcn_global_load_lds(
        (const __attribute__((address_space(1))) void*)(A + (size_t)(m0 + rbase + srow) * K + k0 + scol),
        (__attribute__((address_space(3))) void*)&As[buf][rbase * 64],
        16, 0, 0);
    }
    #pragma unroll
    for (int i = 0; i < BN / 32; i++) {
      int rbase = w * (BN / 4) + i * 8;
      __builtin_amdgcn_global_load_lds(
        (const __attribute__((address_space(1))) void*)(Bt + (size_t)(n0 + rbase + srow) * K + k0 + scol),
        (__attribute__((address_space(3))) void*)&Bs[buf][rbase * 64],
        16, 0, 0);
    }
  };

  f32x4 acc[4][NI] = {};
  stage(0, 0);
  __syncthreads();                          // tile 0 resident
  const int nt = K / 64;
  for (int t = 0; t < nt; t++) {
    const int cur = t & 1;
    if (t + 1 < nt) stage(cur ^ 1, (t + 1) * 64);   // DMA in flight across compute
    #pragma unroll
    for (int kk = 0; kk < 64; kk += 32) {
      bf16x8 af[4], bfr[NI];
      #pragma unroll
      for (int mi = 0; mi < 4; mi++)
        af[mi] = *(const bf16x8*)&As[cur][(wm * 64 + mi * 16 + l15) * 64 + ((((kk >> 3) + g) ^ rsw) << 3)];
      #pragma unroll
      for (int ni = 0; ni < NI; ni++)
        bfr[ni] = *(const bf16x8*)&Bs[cur][(wn * (BN / 2) + ni * 16 + l15) * 64 + ((((kk >> 3) + g) ^ rsw) << 3)];
      #pragma unroll
      for (int mi = 0; mi < 4; mi++)
        #pragma unroll
        for (int ni = 0; ni < NI; ni++)
          acc[mi][ni] = __builtin_amdgcn_mfma_f32_16x16x32_bf16(af[mi], bfr[ni], acc[mi][ni], 0, 0, 0);
    }
    __syncthreads();                        // drains next-tile DMA + protects cur
  }
  #pragma unroll
  for (int mi = 0; mi < 4; mi++) {
    #pragma unroll
    for (int ni = 0; ni < NI; ni++) {
      #pragma unroll
      for (int j = 0; j < 4; j++) {
        int row = m0 + wm * 64 + mi * 16 + g * 4 + j;
        int col = n0 + wn * (BN / 2) + ni * 16 + l15;
        float v = acc[mi][ni][j];
        if (OUT_BF16) {
          if (col < qcols) v *= qscale;     // wave-uniform (block cols span <128)
          ((short*)C)[(size_t)row * N + col] = f2b(v);
        } else {
          ((float*)C)[(size_t)row * N + col] = v;
        }
      }
    }
  }
}

// ---------------- flash attention: 1024 blocks x 4 waves, 64-row q-tiles ----------------
// r10 structure with SINGLE-buffered K/V: LDS 24KB -> 6 blocks/CU (24 waves/CU,
// was 4 blocks/40KB). Rationale: VALU-bound chain at 53% busy / 26% occupancy —
// TLP (more resident blocks) hides the per-tile stage latency that the double
// buffer was hiding intra-block (m238: at high occupancy TLP covers latency).
// G21 involution-swizzled global_load_lds staging (conflicts=0), XCD-chunked
// big-first remap (FETCH 10x), log2-domain softmax, T13 defer-max.
__global__ __launch_bounds__(256, 6) void k_attn(const short* __restrict__ Qkv,
                                                 const short* __restrict__ Vt,
                                                 short* __restrict__ Y) {
  __shared__ short Ks[64 * 64];
  __shared__ short Vs[64 * 64];
  __shared__ short Ps[4][16 * 64];
  const int tid = threadIdx.x;
  const int lane = tid & 63, w = tid >> 6;
  const int l15 = lane & 15, g = lane >> 4;
  const int bx = blockIdx.x;
  const int xcd = bx & 7, idx = bx >> 3;   // 128 logical ids per XCD
  const int bh = xcd * 4 + (idx & 3);      // 4 (b,h) pinned per XCD
  const int qt = 31 - (idx >> 2);          // 64-row q-tile, big-first
  const int b = bh >> 4, h = bh & 15;
  const int q0 = qt * 64;
  const int nkt = qt + 1;
  const short* Qb = Qkv;                   // cols [0,1024), pre-scaled
  const short* Kb = Qkv + DM;              // cols [1024,2048)
  short* PsW = Ps[w];
  const int rsw = l15 & 7;                 // read-side chunk XOR (row&7 == l15&7)

  auto stage = [&](int kt) {
    #pragma unroll
    for (int i = 0; i < 2; i++) {
      int id = tid + 256 * i;
      int r = id >> 3;                     // row 0..63
      int cl = (id ^ r) & 7;               // source chunk = phys ^ (row&7)
      __builtin_amdgcn_global_load_lds(
        (const __attribute__((address_space(1))) void*)(Kb + (size_t)(b * TT + kt * 64 + r) * DQKV + h * 64 + cl * 8),
        (__attribute__((address_space(3))) void*)&Ks[(w * 64 + 256 * i) * 8],
        16, 0, 0);
      __builtin_amdgcn_global_load_lds(
        (const __attribute__((address_space(1))) void*)(Vt + (size_t)(bh * 64 + r) * TT + kt * 64 + cl * 8),
        (__attribute__((address_space(3))) void*)&Vs[(w * 64 + 256 * i) * 8],
        16, 0, 0);
    }
  };

  // Q fragments: rows q0 + w*16 + l15
  bf16x8 aq[2];
  #pragma unroll
  for (int kc = 0; kc < 2; kc++)
    aq[kc] = *(const bf16x8*)(Qb + (size_t)(b * TT + q0 + w * 16 + l15) * DQKV + h * 64 + kc * 32 + 8 * g);

  f32x4 accO[4] = {};
  float m2[4], lp[4];                      // running log2-max, lane-PARTIAL sums
  #pragma unroll
  for (int j = 0; j < 4; j++) { m2[j] = -1e30f; lp[j] = 0.f; }

  for (int kt = 0; kt < nkt; kt++) {
    stage(kt);
    __syncthreads();                       // drains DMA: K/V tile resident

    // S(log2 units) = Qs K^T  (16 q x 64 keys)
    f32x4 accS[4] = {};
    __builtin_amdgcn_s_setprio(1);
    #pragma unroll
    for (int n = 0; n < 4; n++) {
      #pragma unroll
      for (int kc = 0; kc < 2; kc++) {
        bf16x8 bk = *(const bf16x8*)&Ks[(n * 16 + l15) * 64 + (((kc * 4 + g) ^ rsw) << 3)];
        accS[n] = __builtin_amdgcn_mfma_f32_16x16x32_bf16(aq[kc], bk, accS[n], 0, 0, 0);
      }
    }
    __builtin_amdgcn_s_setprio(0);

    // causal mask (diag tile only) + lane-partial row maxima
    float tmaxp[4];
    #pragma unroll
    for (int j = 0; j < 4; j++) tmaxp[j] = -1e30f;
    const int qbase = q0 + w * 16 + g * 4;
    if (kt == qt) {    // diagonal tile (block-uniform branch)
      #pragma unroll
      for (int n = 0; n < 4; n++) {
        int key = kt * 64 + n * 16 + l15;
        #pragma unroll
        for (int j = 0; j < 4; j++) {
          float s = accS[n][j];
          if (key > qbase + j) s = -1e30f;
          accS[n][j] = s;
          tmaxp[j] = fmaxf(tmaxp[j], s);
        }
      }
    } else {
      #pragma unroll
      for (int n = 0; n < 4; n++)
        #pragma unroll
        for (int j = 0; j < 4; j++)
          tmaxp[j] = fmaxf(tmaxp[j], accS[n][j]);
    }

    // T13 defer-max: rescale only when some row's partial max exceeds m2+8
    float dmax = fmaxf(fmaxf(tmaxp[0] - m2[0], tmaxp[1] - m2[1]),
                       fmaxf(tmaxp[2] - m2[2], tmaxp[3] - m2[3]));
    if (!__all(dmax <= 8.0f)) {
      #pragma unroll
      for (int j = 0; j < 4; j++) {
        float t = tmaxp[j];
        #pragma unroll
        for (int off = 1; off < 16; off <<= 1)
          t = fmaxf(t, __shfl_xor(t, off));
        float mnew = fmaxf(m2[j], t);
        float al = exp2f(m2[j] - mnew);
        m2[j] = mnew;
        lp[j] *= al;
        #pragma unroll
        for (int n2 = 0; n2 < 4; n2++) accO[n2][j] *= al;
      }
    }

    // p = 2^(s - m2); partial sums; store truncated bf16 (same XOR involution)
    #pragma unroll
    for (int n = 0; n < 4; n++) {
      #pragma unroll
      for (int j = 0; j < 4; j++) {
        float e = exp2f(accS[n][j] - m2[j]);
        lp[j] += e;
        union { float f; unsigned u; } cv; cv.f = e;
        int row = g * 4 + j;
        int cl = 2 * n + (l15 >> 3);               // logical chunk of col n*16+l15
        PsW[row * 64 + (((cl ^ (row & 7))) << 3) + (l15 & 7)] = (short)(cv.u >> 16);
      }
    }

    __builtin_amdgcn_s_setprio(1);
    #pragma unroll
    for (int kc = 0; kc < 2; kc++) {
      bf16x8 pa = *(const bf16x8*)&PsW[l15 * 64 + (((kc * 4 + g) ^ rsw) << 3)];
      #pragma unroll
      for (int n2 = 0; n2 < 4; n2++) {
        bf16x8 vb = *(const bf16x8*)&Vs[(n2 * 16 + l15) * 64 + (((kc * 4 + g) ^ rsw) << 3)];
        accO[n2] = __builtin_amdgcn_mfma_f32_16x16x32_bf16(pa, vb, accO[n2], 0, 0, 0);
      }
    }
    __builtin_amdgcn_s_setprio(0);

    if (kt + 1 < nkt) __syncthreads();     // all done reading K/V before overwrite
  }

  // reduce lane-partial sums once, normalize, write Y
  float lr[4];
  #pragma unroll
  for (int j = 0; j < 4; j++) {
    float s = lp[j];
    #pragma unroll
    for (int off = 1; off < 16; off <<= 1)
      s += __shfl_xor(s, off);
    lr[j] = s;
  }
  const int orow = b * TT + q0 + w * 16;
  #pragma unroll
  for (int n2 = 0; n2 < 4; n2++) {
    #pragma unroll
    for (int j = 0; j < 4; j++) {
      float v = accO[n2][j] / lr[j];
      Y[(size_t)(orow + g * 4 + j) * DM + h * 64 + n2 * 16 + l15] = f2b(v);
    }
  }
}

extern "C" void kernel_launch(void* const* d_in, const int* in_sizes, int n_in,
                              void* d_out, int out_size, void* d_ws, size_t ws_size,
                              hipStream_t stream) {
  const float* x  = (const float*)d_in[0];
  const float* Wq = (const float*)d_in[1];
  const float* Wk = (const float*)d_in[2];
  const float* Wv = (const float*)d_in[3];
  const float* Wo = (const float*)d_in[4];
  float* out = (float*)d_out;

  char* ws = (char*)d_ws;
  size_t off = 0;
  auto alloc = [&](size_t bytes) {
    char* p = ws + off;
    off += (bytes + 255) & ~(size_t)255;
    return p;
  };
  short* xb    = (short*)alloc((size_t)NTOK * DM * 2);    // also reused as Y
  short* WqkvT = (short*)alloc((size_t)DQKV * DM * 2);    // [3072][1024]
  short* WoT   = (short*)alloc((size_t)DM * DM * 2);
  short* Qkv   = (short*)alloc((size_t)NTOK * DQKV * 2);  // [4096][3072]
  short* Vt    = (short*)alloc((size_t)NTOK * DM * 2);    // [32][64][2048]
  short* Yb    = xb;   // x dead after QKV GEMM; reuse region for Y
  if (off > ws_size) return;   // workspace too small -> loud failure

  k_convert<<<(NTOK * DM) / (256 * 8), 256, 0, stream>>>(x, xb, NTOK * DM);
  k_transpose_w4<<<dim3(DM / 64, DM / 64, 4), 256, 0, stream>>>(Wq, Wk, Wv, Wo, WqkvT, WoT);

  // fused QKV GEMM; Q cols pre-scaled by 0.125*log2e (softmax in log2 domain)
  const float QSC = 0.125f * 1.44269504088896f;
  k_gemm_lds<1, 128><<<dim3((DQKV / 128) * (NTOK / 128)), 256, 0, stream>>>(xb, WqkvT, Qkv, NTOK, DQKV, DM, DM, QSC);

  k_transpose_v<<<dim3(TT / 64, BB * NH), 256, 0, stream>>>(Qkv + 2048, Vt);
  k_attn<<<dim3(1024), 256, 0, stream>>>(Qkv, Vt, Yb);

  // out projection: [4096][1024] x [1024][1024]^T -> fp32 out (128x64 tiles, 1D grid)
  k_gemm_lds<0, 64><<<dim3((DM / 64) * (NTOK / 128)), 256, 0, stream>>>(Yb, WoT, out, NTOK, DM, DM, 0, 1.0f);
}

// Round 13
// 115.408 us; speedup vs baseline: 1.5310x; 1.5310x over previous
//
#include <hip/hip_runtime.h>

#define DM 1024
#define NH 16
#define TT 2048
#define BB 2
#define NTOK (BB*TT)
#define DQKV 3072

typedef __attribute__((ext_vector_type(8))) short bf16x8;   // 8 bf16 (4 VGPRs)
typedef __attribute__((ext_vector_type(4))) float f32x4;    // MFMA C/D
typedef __attribute__((ext_vector_type(4))) int  int4v;     // 16B chunk

static __device__ __forceinline__ short f2b(float f) {
  union { float f; unsigned u; } v; v.f = f;
  unsigned r = v.u + 0x7FFFu + ((v.u >> 16) & 1u);   // RNE fp32->bf16
  return (short)(r >> 16);
}

// ---------------- fp32 -> bf16 convert (x) ----------------
__global__ __launch_bounds__(256) void k_convert(const float* __restrict__ in,
                                                 short* __restrict__ out, int n) {
  int i = (blockIdx.x * 256 + threadIdx.x) * 8;
  if (i >= n) return;
  float4 a = *(const float4*)(in + i);
  float4 b = *(const float4*)(in + i + 4);
  bf16x8 o;
  o[0]=f2b(a.x); o[1]=f2b(a.y); o[2]=f2b(a.z); o[3]=f2b(a.w);
  o[4]=f2b(b.x); o[5]=f2b(b.y); o[6]=f2b(b.z); o[7]=f2b(b.w);
  *(bf16x8*)(out + i) = o;
}

// ---------------- all 4 weights [K][N] fp32 -> [N][K] bf16, one launch ----------------
__global__ __launch_bounds__(256) void k_transpose_w4(const float* __restrict__ Wq,
                                                      const float* __restrict__ Wk,
                                                      const float* __restrict__ Wv,
                                                      const float* __restrict__ Wo,
                                                      short* __restrict__ WqkvT,
                                                      short* __restrict__ WoT) {
  __shared__ short t[64][72];
  const int z = blockIdx.z;
  const float* W = (z == 0) ? Wq : (z == 1) ? Wk : (z == 2) ? Wv : Wo;
  short* Wt = (z < 3) ? WqkvT : WoT;
  const int row0 = (z < 3) ? z * 1024 : 0;
  int tid = threadIdx.x;
  int n0 = blockIdx.x * 64, k0 = blockIdx.y * 64;
  #pragma unroll
  for (int i = 0; i < 4; i++) {
    int id = tid + 256 * i;
    int r = id >> 4;        // k row within tile
    int c = id & 15;        // float4 chunk along n
    float4 v = *(const float4*)(W + (size_t)(k0 + r) * DM + n0 + c * 4);
    t[c*4+0][r] = f2b(v.x);
    t[c*4+1][r] = f2b(v.y);
    t[c*4+2][r] = f2b(v.z);
    t[c*4+3][r] = f2b(v.w);
  }
  __syncthreads();
  #pragma unroll
  for (int i = 0; i < 2; i++) {
    int id = tid + 256 * i;
    int r = id >> 3;        // n row
    int c = id & 7;         // 8-elem chunk along k
    bf16x8 o = *(const bf16x8*)&t[r][c * 8];
    *(bf16x8*)(Wt + (size_t)(row0 + n0 + r) * DM + k0 + c * 8) = o;
  }
}

// ---------------- V (cols of Qkv) -> Vt [BB*NH][64][TT] bf16, KEY-SLOT PERMUTED ----------------
// Within each 64-key tile, output column slot k holds key perm(k)=(k&3)*16+(k>>2).
// P's A-fragments use the same slot permutation (MFMA sums over k -> exact), which
// makes each lane's P row-values contiguous -> ds_write_b64 P staging in k_attn.
__global__ __launch_bounds__(256) void k_transpose_v(const short* __restrict__ V,
                                                     short* __restrict__ Vt) {
  __shared__ short t[64][72];
  int tid = threadIdx.x;
  int bh = blockIdx.y;
  int b = bh >> 4, h = bh & 15;
  int t0 = blockIdx.x * 64;
  #pragma unroll
  for (int i = 0; i < 2; i++) {
    int id = tid + 256 * i;
    int r = id >> 3;        // t row (key within tile)
    int c = id & 7;         // 8-bf16 chunk along d
    int kp = ((r & 15) << 2) | (r >> 4);   // slot = perm^{-1}(key)
    bf16x8 v = *(const bf16x8*)(V + (size_t)(b * TT + t0 + r) * DQKV + h * 64 + c * 8);
    #pragma unroll
    for (int e = 0; e < 8; e++) t[c * 8 + e][kp] = v[e];
  }
  __syncthreads();
  #pragma unroll
  for (int i = 0; i < 2; i++) {
    int id = tid + 256 * i;
    int r = id >> 3;        // d row
    int c = id & 7;         // slot chunk
    bf16x8 o = *(const bf16x8*)&t[r][c * 8];
    *(bf16x8*)(Vt + (size_t)(bh * 64 + r) * TT + t0 + c * 8) = o;
  }
}

// ---------------- GEMM NT: C[M][N] = A[M][K] * Bt[N][K]^T ----------------
// r10 version: 2-phase double-buffered, global_load_lds staging, G21 involution
// swizzle, T1 XCD-chunked bijective remap, __syncthreads sync.
template<int OUT_BF16, int BN>
__global__ __launch_bounds__(256) void k_gemm_lds(const short* __restrict__ A,
                                                  const short* __restrict__ Bt,
                                                  void* __restrict__ C,
                                                  int M, int N, int K,
                                                  int qcols, float qscale) {
  __shared__ short As[2][128 * 64];
  __shared__ short Bs[2][BN * 64];
  constexpr int NI = BN / 32;               // 16-wide n-frags per wave
  const int tid = threadIdx.x;
  const int lane = tid & 63, w = tid >> 6;
  const int wm = w >> 1, wn = w & 1;        // 2x2 wave grid
  const int l15 = lane & 15, g = lane >> 4;
  const int nx = N / BN;
  const int cx = nx >> 3;
  const int bid = blockIdx.x;
  const int xcd = bid & 7, k_ = bid >> 3;
  const int bx = xcd * cx + (k_ % cx), by = k_ / cx;
  const int m0 = by * 128, n0 = bx * BN;
  const int srow = lane >> 3;               // 0..7 row within 8-row segment
  const int scol = ((lane & 7) ^ srow) * 8; // pre-swizzled SOURCE chunk (shorts)
  const int rsw = l15 & 7;                  // read-side XOR (row&7 == l15&7)

  auto stage = [&](int buf, int k0) {
    #pragma unroll
    for (int i = 0; i < 4; i++) {
      int rbase = w * 32 + i * 8;
      __builtin_amdgcn_global_load_lds(
        (const __attribute__((address_space(1))) void*)(A + (size_t)(m0 + rbase + srow) * K + k0 + scol),
        (__attribute__((address_space(3))) void*)&As[buf][rbase * 64],
        16, 0, 0);
    }
    #pragma unroll
    for (int i = 0; i < BN / 32; i++) {
      int rbase = w * (BN / 4) + i * 8;
      __builtin_amdgcn_global_load_lds(
        (const __attribute__((address_space(1))) void*)(Bt + (size_t)(n0 + rbase + srow) * K + k0 + scol),
        (__attribute__((address_space(3))) void*)&Bs[buf][rbase * 64],
        16, 0, 0);
    }
  };

  f32x4 acc[4][NI] = {};
  stage(0, 0);
  __syncthreads();                          // tile 0 resident
  const int nt = K / 64;
  for (int t = 0; t < nt; t++) {
    const int cur = t & 1;
    if (t + 1 < nt) stage(cur ^ 1, (t + 1) * 64);   // DMA in flight across compute
    #pragma unroll
    for (int kk = 0; kk < 64; kk += 32) {
      bf16x8 af[4], bfr[NI];
      #pragma unroll
      for (int mi = 0; mi < 4; mi++)
        af[mi] = *(const bf16x8*)&As[cur][(wm * 64 + mi * 16 + l15) * 64 + ((((kk >> 3) + g) ^ rsw) << 3)];
      #pragma unroll
      for (int ni = 0; ni < NI; ni++)
        bfr[ni] = *(const bf16x8*)&Bs[cur][(wn * (BN / 2) + ni * 16 + l15) * 64 + ((((kk >> 3) + g) ^ rsw) << 3)];
      #pragma unroll
      for (int mi = 0; mi < 4; mi++)
        #pragma unroll
        for (int ni = 0; ni < NI; ni++)
          acc[mi][ni] = __builtin_amdgcn_mfma_f32_16x16x32_bf16(af[mi], bfr[ni], acc[mi][ni], 0, 0, 0);
    }
    __syncthreads();                        // drains next-tile DMA + protects cur
  }
  #pragma unroll
  for (int mi = 0; mi < 4; mi++) {
    #pragma unroll
    for (int ni = 0; ni < NI; ni++) {
      #pragma unroll
      for (int j = 0; j < 4; j++) {
        int row = m0 + wm * 64 + mi * 16 + g * 4 + j;
        int col = n0 + wn * (BN / 2) + ni * 16 + l15;
        float v = acc[mi][ni][j];
        if (OUT_BF16) {
          if (col < qcols) v *= qscale;     // wave-uniform (block cols span <128)
          ((short*)C)[(size_t)row * N + col] = f2b(v);
        } else {
          ((float*)C)[(size_t)row * N + col] = v;
        }
      }
    }
  }
}

// ---------------- flash attention: 1024 blocks x 4 waves, 64-row q-tiles ----------------
// r10 skeleton (double-buffered G21-swizzled global_load_lds K/V, 40KB LDS =
// 4 blocks/CU, XCD-chunked big-first remap, log2-domain softmax, T13 defer-max).
// NEW vs r10: (a) key-slot-permuted P staging -> 4 ds_write_b64/tile instead of
// 16 ds_write_b16 (V columns permuted identically by k_transpose_v, exact);
// (b) accL row-sums via MFMA-ones -> no lp adds, no final cross-lane reduce.
__global__ __launch_bounds__(256) void k_attn(const short* __restrict__ Qkv,
                                              const short* __restrict__ Vt,
                                              short* __restrict__ Y) {
  __shared__ short Ks[2][64 * 64];
  __shared__ short Vs[2][64 * 64];
  __shared__ short Ps[4][16 * 64];
  const int tid = threadIdx.x;
  const int lane = tid & 63, w = tid >> 6;
  const int l15 = lane & 15, g = lane >> 4;
  const int bx = blockIdx.x;
  const int xcd = bx & 7, idx = bx >> 3;   // 128 logical ids per XCD
  const int bh = xcd * 4 + (idx & 3);      // 4 (b,h) pinned per XCD
  const int qt = 31 - (idx >> 2);          // 64-row q-tile, big-first
  const int b = bh >> 4, h = bh & 15;
  const int q0 = qt * 64;
  const int nkt = qt + 1;
  const short* Qb = Qkv;                   // cols [0,1024), pre-scaled
  const short* Kb = Qkv + DM;              // cols [1024,2048)
  short* PsW = Ps[w];
  const int rsw = l15 & 7;                 // read-side chunk XOR (row&7 == l15&7)

  const bf16x8 vones = {0x3F80, 0x3F80, 0x3F80, 0x3F80, 0x3F80, 0x3F80, 0x3F80, 0x3F80};

  auto stage = [&](int buf, int kt) {
    #pragma unroll
    for (int i = 0; i < 2; i++) {
      int id = tid + 256 * i;
      int r = id >> 3;                     // row 0..63
      int cl = (id ^ r) & 7;               // source chunk = phys ^ (row&7)
      __builtin_amdgcn_global_load_lds(
        (const __attribute__((address_space(1))) void*)(Kb + (size_t)(b * TT + kt * 64 + r) * DQKV + h * 64 + cl * 8),
        (__attribute__((address_space(3))) void*)&Ks[buf][(w * 64 + 256 * i) * 8],
        16, 0, 0);
      __builtin_amdgcn_global_load_lds(
        (const __attribute__((address_space(1))) void*)(Vt + (size_t)(bh * 64 + r) * TT + kt * 64 + cl * 8),
        (__attribute__((address_space(3))) void*)&Vs[buf][(w * 64 + 256 * i) * 8],
        16, 0, 0);
    }
  };

  // Q fragments: rows q0 + w*16 + l15
  bf16x8 aq[2];
  #pragma unroll
  for (int kc = 0; kc < 2; kc++)
    aq[kc] = *(const bf16x8*)(Qb + (size_t)(b * TT + q0 + w * 16 + l15) * DQKV + h * 64 + kc * 32 + 8 * g);

  f32x4 accO[4] = {};
  f32x4 accL = {};                         // MFMA-ones row sums
  float m2[4];
  #pragma unroll
  for (int j = 0; j < 4; j++) m2[j] = -1e30f;

  stage(0, 0);
  __syncthreads();

  for (int kt = 0; kt < nkt; kt++) {
    const int cur = kt & 1;
    if (kt + 1 < nkt) stage(cur ^ 1, kt + 1);

    // S(log2 units) = Qs K^T  (16 q x 64 keys)
    f32x4 accS[4] = {};
    __builtin_amdgcn_s_setprio(1);
    #pragma unroll
    for (int n = 0; n < 4; n++) {
      #pragma unroll
      for (int kc = 0; kc < 2; kc++) {
        bf16x8 bk = *(const bf16x8*)&Ks[cur][(n * 16 + l15) * 64 + (((kc * 4 + g) ^ rsw) << 3)];
        accS[n] = __builtin_amdgcn_mfma_f32_16x16x32_bf16(aq[kc], bk, accS[n], 0, 0, 0);
      }
    }
    __builtin_amdgcn_s_setprio(0);

    // causal mask (diag tile only) + lane-partial row maxima
    float tmaxp[4];
    #pragma unroll
    for (int j = 0; j < 4; j++) tmaxp[j] = -1e30f;
    const int qbase = q0 + w * 16 + g * 4;
    if (kt == qt) {    // diagonal tile (block-uniform branch)
      #pragma unroll
      for (int n = 0; n < 4; n++) {
        int key = kt * 64 + n * 16 + l15;
        #pragma unroll
        for (int j = 0; j < 4; j++) {
          float s = accS[n][j];
          if (key > qbase + j) s = -1e30f;
          accS[n][j] = s;
          tmaxp[j] = fmaxf(tmaxp[j], s);
        }
      }
    } else {
      #pragma unroll
      for (int n = 0; n < 4; n++)
        #pragma unroll
        for (int j = 0; j < 4; j++)
          tmaxp[j] = fmaxf(tmaxp[j], accS[n][j]);
    }

    // T13 defer-max: rescale only when some row's partial max exceeds m2+8
    float dmax = fmaxf(fmaxf(tmaxp[0] - m2[0], tmaxp[1] - m2[1]),
                       fmaxf(tmaxp[2] - m2[2], tmaxp[3] - m2[3]));
    if (!__all(dmax <= 8.0f)) {
      #pragma unroll
      for (int j = 0; j < 4; j++) {
        float t = tmaxp[j];
        #pragma unroll
        for (int off = 1; off < 16; off <<= 1)
          t = fmaxf(t, __shfl_xor(t, off));
        float mnew = fmaxf(m2[j], t);
        float al = exp2f(m2[j] - mnew);
        m2[j] = mnew;
        accL[j] *= al;
        #pragma unroll
        for (int n2 = 0; n2 < 4; n2++) accO[n2][j] *= al;
      }
    }

    // p = 2^(s - m2); slot-permuted pack: lane's 4 values per row are contiguous
    // (slot 4*l15+n holds key n*16+l15) -> one ds_write_b64 per row j.
    #pragma unroll
    for (int j = 0; j < 4; j++) {
      const int row = g * 4 + j;
      union { float f; unsigned u; } c0, c1, c2, c3;
      c0.f = exp2f(accS[0][j] - m2[j]);
      c1.f = exp2f(accS[1][j] - m2[j]);
      c2.f = exp2f(accS[2][j] - m2[j]);
      c3.f = exp2f(accS[3][j] - m2[j]);
      int2 pk;
      pk.x = (int)((c0.u >> 16) | (c1.u & 0xFFFF0000u));   // slots 4*l15+0,+1
      pk.y = (int)((c2.u >> 16) | (c3.u & 0xFFFF0000u));   // slots 4*l15+2,+3
      const int c8 = l15 ^ ((row & 7) << 1);               // 8B-chunk swizzle
      *(int2*)&PsW[row * 64 + (c8 << 2)] = pk;
    }

    __builtin_amdgcn_s_setprio(1);
    #pragma unroll
    for (int kc = 0; kc < 2; kc++) {
      bf16x8 pa = *(const bf16x8*)&PsW[l15 * 64 + (((kc * 4 + g) ^ rsw) << 3)];
      #pragma unroll
      for (int n2 = 0; n2 < 4; n2++) {
        bf16x8 vb = *(const bf16x8*)&Vs[cur][(n2 * 16 + l15) * 64 + (((kc * 4 + g) ^ rsw) << 3)];
        accO[n2] = __builtin_amdgcn_mfma_f32_16x16x32_bf16(pa, vb, accO[n2], 0, 0, 0);
      }
      accL = __builtin_amdgcn_mfma_f32_16x16x32_bf16(pa, vones, accL, 0, 0, 0);
    }
    __builtin_amdgcn_s_setprio(0);

    // barrier publishes the prefetched buffer (drains DMA vmcnt) and protects Ps
    __syncthreads();
  }

  // normalize (accL[j] = rowsum in every lane; no cross-lane reduce) + write Y
  float inv[4];
  #pragma unroll
  for (int j = 0; j < 4; j++) inv[j] = 1.0f / accL[j];
  const int orow = b * TT + q0 + w * 16;
  #pragma unroll
  for (int n2 = 0; n2 < 4; n2++) {
    #pragma unroll
    for (int j = 0; j < 4; j++) {
      float v = accO[n2][j] * inv[j];
      Y[(size_t)(orow + g * 4 + j) * DM + h * 64 + n2 * 16 + l15] = f2b(v);
    }
  }
}

extern "C" void kernel_launch(void* const* d_in, const int* in_sizes, int n_in,
                              void* d_out, int out_size, void* d_ws, size_t ws_size,
                              hipStream_t stream) {
  const float* x  = (const float*)d_in[0];
  const float* Wq = (const float*)d_in[1];
  const float* Wk = (const float*)d_in[2];
  const float* Wv = (const float*)d_in[3];
  const float* Wo = (const float*)d_in[4];
  float* out = (float*)d_out;

  char* ws = (char*)d_ws;
  size_t off = 0;
  auto alloc = [&](size_t bytes) {
    char* p = ws + off;
    off += (bytes + 255) & ~(size_t)255;
    return p;
  };
  short* xb    = (short*)alloc((size_t)NTOK * DM * 2);    // also reused as Y
  short* WqkvT = (short*)alloc((size_t)DQKV * DM * 2);    // [3072][1024]
  short* WoT   = (short*)alloc((size_t)DM * DM * 2);
  short* Qkv   = (short*)alloc((size_t)NTOK * DQKV * 2);  // [4096][3072]
  short* Vt    = (short*)alloc((size_t)NTOK * DM * 2);    // [32][64][2048]
  short* Yb    = xb;   // x dead after QKV GEMM; reuse region for Y
  if (off > ws_size) return;   // workspace too small -> loud failure

  k_convert<<<(NTOK * DM) / (256 * 8), 256, 0, stream>>>(x, xb, NTOK * DM);
  k_transpose_w4<<<dim3(DM / 64, DM / 64, 4), 256, 0, stream>>>(Wq, Wk, Wv, Wo, WqkvT, WoT);

  // fused QKV GEMM; Q cols pre-scaled by 0.125*log2e (softmax in log2 domain)
  const float QSC = 0.125f * 1.44269504088896f;
  k_gemm_lds<1, 128><<<dim3((DQKV / 128) * (NTOK / 128)), 256, 0, stream>>>(xb, WqkvT, Qkv, NTOK, DQKV, DM, DM, QSC);

  k_transpose_v<<<dim3(TT / 64, BB * NH), 256, 0, stream>>>(Qkv + 2048, Vt);
  k_attn<<<dim3(1024), 256, 0, stream>>>(Qkv, Vt, Yb);

  // out projection: [4096][1024] x [1024][1024]^T -> fp32 out (128x64 tiles, 1D grid)
  k_gemm_lds<0, 64><<<dim3((DM / 64) * (NTOK / 128)), 256, 0, stream>>>(Yb, WoT, out, NTOK, DM, DM, 0, 1.0f);
}

// Round 14
// 110.926 us; speedup vs baseline: 1.5929x; 1.0404x over previous
//
#include <hip/hip_runtime.h>

#define DM 1024
#define NH 16
#define TT 2048
#define BB 2
#define NTOK (BB*TT)
#define DQKV 3072

typedef __attribute__((ext_vector_type(8))) short bf16x8;   // 8 bf16 (4 VGPRs)
typedef __attribute__((ext_vector_type(4))) float f32x4;    // MFMA C/D
typedef __attribute__((ext_vector_type(4))) int  int4v;     // 16B chunk

static __device__ __forceinline__ short f2b(float f) {
  union { float f; unsigned u; } v; v.f = f;
  unsigned r = v.u + 0x7FFFu + ((v.u >> 16) & 1u);   // RNE fp32->bf16
  return (short)(r >> 16);
}

// ---------------- fp32 -> bf16 convert (x) ----------------
__global__ __launch_bounds__(256) void k_convert(const float* __restrict__ in,
                                                 short* __restrict__ out, int n) {
  int i = (blockIdx.x * 256 + threadIdx.x) * 8;
  if (i >= n) return;
  float4 a = *(const float4*)(in + i);
  float4 b = *(const float4*)(in + i + 4);
  bf16x8 o;
  o[0]=f2b(a.x); o[1]=f2b(a.y); o[2]=f2b(a.z); o[3]=f2b(a.w);
  o[4]=f2b(b.x); o[5]=f2b(b.y); o[6]=f2b(b.z); o[7]=f2b(b.w);
  *(bf16x8*)(out + i) = o;
}

// ---------------- all 4 weights [K][N] fp32 -> [N][K] bf16, one launch ----------------
__global__ __launch_bounds__(256) void k_transpose_w4(const float* __restrict__ Wq,
                                                      const float* __restrict__ Wk,
                                                      const float* __restrict__ Wv,
                                                      const float* __restrict__ Wo,
                                                      short* __restrict__ WqkvT,
                                                      short* __restrict__ WoT) {
  __shared__ short t[64][72];
  const int z = blockIdx.z;
  const float* W = (z == 0) ? Wq : (z == 1) ? Wk : (z == 2) ? Wv : Wo;
  short* Wt = (z < 3) ? WqkvT : WoT;
  const int row0 = (z < 3) ? z * 1024 : 0;
  int tid = threadIdx.x;
  int n0 = blockIdx.x * 64, k0 = blockIdx.y * 64;
  #pragma unroll
  for (int i = 0; i < 4; i++) {
    int id = tid + 256 * i;
    int r = id >> 4;        // k row within tile
    int c = id & 15;        // float4 chunk along n
    float4 v = *(const float4*)(W + (size_t)(k0 + r) * DM + n0 + c * 4);
    t[c*4+0][r] = f2b(v.x);
    t[c*4+1][r] = f2b(v.y);
    t[c*4+2][r] = f2b(v.z);
    t[c*4+3][r] = f2b(v.w);
  }
  __syncthreads();
  #pragma unroll
  for (int i = 0; i < 2; i++) {
    int id = tid + 256 * i;
    int r = id >> 3;        // n row
    int c = id & 7;         // 8-elem chunk along k
    bf16x8 o = *(const bf16x8*)&t[r][c * 8];
    *(bf16x8*)(Wt + (size_t)(row0 + n0 + r) * DM + k0 + c * 8) = o;
  }
}

// ---------------- V (cols of Qkv) -> Vt [BB*NH][64][TT] bf16, KEY-SLOT PERMUTED ----------------
// Within each 64-key tile, output column slot k holds key perm(k)=(k&3)*16+(k>>2).
// P's A-fragments use the same slot permutation (MFMA sums over k -> exact), which
// makes each lane's P row-values contiguous -> ds_write_b64 P staging in k_attn.
__global__ __launch_bounds__(256) void k_transpose_v(const short* __restrict__ V,
                                                     short* __restrict__ Vt) {
  __shared__ short t[64][72];
  int tid = threadIdx.x;
  int bh = blockIdx.y;
  int b = bh >> 4, h = bh & 15;
  int t0 = blockIdx.x * 64;
  #pragma unroll
  for (int i = 0; i < 2; i++) {
    int id = tid + 256 * i;
    int r = id >> 3;        // t row (key within tile)
    int c = id & 7;         // 8-bf16 chunk along d
    int kp = ((r & 15) << 2) | (r >> 4);   // slot = perm^{-1}(key)
    bf16x8 v = *(const bf16x8*)(V + (size_t)(b * TT + t0 + r) * DQKV + h * 64 + c * 8);
    #pragma unroll
    for (int e = 0; e < 8; e++) t[c * 8 + e][kp] = v[e];
  }
  __syncthreads();
  #pragma unroll
  for (int i = 0; i < 2; i++) {
    int id = tid + 256 * i;
    int r = id >> 3;        // d row
    int c = id & 7;         // slot chunk
    bf16x8 o = *(const bf16x8*)&t[r][c * 8];
    *(bf16x8*)(Vt + (size_t)(bh * 64 + r) * TT + t0 + c * 8) = o;
  }
}

// ---------------- GEMM NT: C[M][N] = A[M][K] * Bt[N][K]^T ----------------
// 2-phase double-buffered, global_load_lds staging, G21 involution swizzle,
// T1 XCD-chunked bijective remap. bf16 epilogue: LDS roundtrip (reuse As) ->
// coalesced bf16x8 stores (was 16 scalar 2B stores/thread).
template<int OUT_BF16, int BN>
__global__ __launch_bounds__(256) void k_gemm_lds(const short* __restrict__ A,
                                                  const short* __restrict__ Bt,
                                                  void* __restrict__ C,
                                                  int M, int N, int K,
                                                  int qcols, float qscale) {
  __shared__ short As[2][128 * 64];
  __shared__ short Bs[2][BN * 64];
  constexpr int NI = BN / 32;               // 16-wide n-frags per wave
  const int tid = threadIdx.x;
  const int lane = tid & 63, w = tid >> 6;
  const int wm = w >> 1, wn = w & 1;        // 2x2 wave grid
  const int l15 = lane & 15, g = lane >> 4;
  const int nx = N / BN;
  const int cx = nx >> 3;
  const int bid = blockIdx.x;
  const int xcd = bid & 7, k_ = bid >> 3;
  const int bx = xcd * cx + (k_ % cx), by = k_ / cx;
  const int m0 = by * 128, n0 = bx * BN;
  const int srow = lane >> 3;               // 0..7 row within 8-row segment
  const int scol = ((lane & 7) ^ srow) * 8; // pre-swizzled SOURCE chunk (shorts)
  const int rsw = l15 & 7;                  // read-side XOR (row&7 == l15&7)

  auto stage = [&](int buf, int k0) {
    #pragma unroll
    for (int i = 0; i < 4; i++) {
      int rbase = w * 32 + i * 8;
      __builtin_amdgcn_global_load_lds(
        (const __attribute__((address_space(1))) void*)(A + (size_t)(m0 + rbase + srow) * K + k0 + scol),
        (__attribute__((address_space(3))) void*)&As[buf][rbase * 64],
        16, 0, 0);
    }
    #pragma unroll
    for (int i = 0; i < BN / 32; i++) {
      int rbase = w * (BN / 4) + i * 8;
      __builtin_amdgcn_global_load_lds(
        (const __attribute__((address_space(1))) void*)(Bt + (size_t)(n0 + rbase + srow) * K + k0 + scol),
        (__attribute__((address_space(3))) void*)&Bs[buf][rbase * 64],
        16, 0, 0);
    }
  };

  f32x4 acc[4][NI] = {};
  stage(0, 0);
  __syncthreads();                          // tile 0 resident
  const int nt = K / 64;
  for (int t = 0; t < nt; t++) {
    const int cur = t & 1;
    if (t + 1 < nt) stage(cur ^ 1, (t + 1) * 64);   // DMA in flight across compute
    #pragma unroll
    for (int kk = 0; kk < 64; kk += 32) {
      bf16x8 af[4], bfr[NI];
      #pragma unroll
      for (int mi = 0; mi < 4; mi++)
        af[mi] = *(const bf16x8*)&As[cur][(wm * 64 + mi * 16 + l15) * 64 + ((((kk >> 3) + g) ^ rsw) << 3)];
      #pragma unroll
      for (int ni = 0; ni < NI; ni++)
        bfr[ni] = *(const bf16x8*)&Bs[cur][(wn * (BN / 2) + ni * 16 + l15) * 64 + ((((kk >> 3) + g) ^ rsw) << 3)];
      #pragma unroll
      for (int mi = 0; mi < 4; mi++)
        #pragma unroll
        for (int ni = 0; ni < NI; ni++)
          acc[mi][ni] = __builtin_amdgcn_mfma_f32_16x16x32_bf16(af[mi], bfr[ni], acc[mi][ni], 0, 0, 0);
    }
    __syncthreads();                        // drains next-tile DMA + protects cur
  }

  if (OUT_BF16) {
    // LDS roundtrip epilogue: scatter acc into As scratch (once), then
    // coalesced bf16x8 row stores. 128*BN shorts <= 32KB fits As[2][...].
    short* Cs = &As[0][0];
    #pragma unroll
    for (int mi = 0; mi < 4; mi++) {
      #pragma unroll
      for (int ni = 0; ni < NI; ni++) {
        #pragma unroll
        for (int j = 0; j < 4; j++) {
          int row = wm * 64 + mi * 16 + g * 4 + j;
          int col = wn * (BN / 2) + ni * 16 + l15;
          float v = acc[mi][ni][j];
          if (n0 + col < qcols) v *= qscale;   // wave-uniform (64 | qcols)
          Cs[row * BN + col] = f2b(v);
        }
      }
    }
    __syncthreads();
    constexpr int UNITS = 128 * BN / 8;        // 16B chunks in the C tile
    #pragma unroll
    for (int u = tid; u < UNITS; u += 256) {
      int row = u / (BN / 8), ch = u % (BN / 8);
      bf16x8 vv = *(const bf16x8*)&Cs[row * BN + ch * 8];
      *(bf16x8*)((short*)C + (size_t)(m0 + row) * N + n0 + ch * 8) = vv;
    }
  } else {
    #pragma unroll
    for (int mi = 0; mi < 4; mi++) {
      #pragma unroll
      for (int ni = 0; ni < NI; ni++) {
        #pragma unroll
        for (int j = 0; j < 4; j++) {
          int row = m0 + wm * 64 + mi * 16 + g * 4 + j;
          int col = n0 + wn * (BN / 2) + ni * 16 + l15;
          ((float*)C)[(size_t)row * N + col] = acc[mi][ni][j];
        }
      }
    }
  }
}

// ---------------- flash attention: 1024 blocks x 4 waves, 64-row q-tiles ----------------
// r13 structure (double-buffered G21-swizzled global_load_lds K/V, 40KB LDS =
// 4 blocks/CU, XCD-chunked big-first remap, log2-domain softmax, T13 defer-max,
// slot-permuted ds_write_b64 P staging, accL row-sums via MFMA-ones).
// NEW: Y epilogue via wave-private PsW roundtrip -> 2 coalesced bf16x8 stores
// per thread (was 16 scalar 2B stores).
__global__ __launch_bounds__(256) void k_attn(const short* __restrict__ Qkv,
                                              const short* __restrict__ Vt,
                                              short* __restrict__ Y) {
  __shared__ short Ks[2][64 * 64];
  __shared__ short Vs[2][64 * 64];
  __shared__ short Ps[4][16 * 64];
  const int tid = threadIdx.x;
  const int lane = tid & 63, w = tid >> 6;
  const int l15 = lane & 15, g = lane >> 4;
  const int bx = blockIdx.x;
  const int xcd = bx & 7, idx = bx >> 3;   // 128 logical ids per XCD
  const int bh = xcd * 4 + (idx & 3);      // 4 (b,h) pinned per XCD
  const int qt = 31 - (idx >> 2);          // 64-row q-tile, big-first
  const int b = bh >> 4, h = bh & 15;
  const int q0 = qt * 64;
  const int nkt = qt + 1;
  const short* Qb = Qkv;                   // cols [0,1024), pre-scaled
  const short* Kb = Qkv + DM;              // cols [1024,2048)
  short* PsW = Ps[w];
  const int rsw = l15 & 7;                 // read-side chunk XOR (row&7 == l15&7)

  const bf16x8 vones = {0x3F80, 0x3F80, 0x3F80, 0x3F80, 0x3F80, 0x3F80, 0x3F80, 0x3F80};

  auto stage = [&](int buf, int kt) {
    #pragma unroll
    for (int i = 0; i < 2; i++) {
      int id = tid + 256 * i;
      int r = id >> 3;                     // row 0..63
      int cl = (id ^ r) & 7;               // source chunk = phys ^ (row&7)
      __builtin_amdgcn_global_load_lds(
        (const __attribute__((address_space(1))) void*)(Kb + (size_t)(b * TT + kt * 64 + r) * DQKV + h * 64 + cl * 8),
        (__attribute__((address_space(3))) void*)&Ks[buf][(w * 64 + 256 * i) * 8],
        16, 0, 0);
      __builtin_amdgcn_global_load_lds(
        (const __attribute__((address_space(1))) void*)(Vt + (size_t)(bh * 64 + r) * TT + kt * 64 + cl * 8),
        (__attribute__((address_space(3))) void*)&Vs[buf][(w * 64 + 256 * i) * 8],
        16, 0, 0);
    }
  };

  // Q fragments: rows q0 + w*16 + l15
  bf16x8 aq[2];
  #pragma unroll
  for (int kc = 0; kc < 2; kc++)
    aq[kc] = *(const bf16x8*)(Qb + (size_t)(b * TT + q0 + w * 16 + l15) * DQKV + h * 64 + kc * 32 + 8 * g);

  f32x4 accO[4] = {};
  f32x4 accL = {};                         // MFMA-ones row sums
  float m2[4];
  #pragma unroll
  for (int j = 0; j < 4; j++) m2[j] = -1e30f;

  stage(0, 0);
  __syncthreads();

  for (int kt = 0; kt < nkt; kt++) {
    const int cur = kt & 1;
    if (kt + 1 < nkt) stage(cur ^ 1, kt + 1);

    // S(log2 units) = Qs K^T  (16 q x 64 keys)
    f32x4 accS[4] = {};
    __builtin_amdgcn_s_setprio(1);
    #pragma unroll
    for (int n = 0; n < 4; n++) {
      #pragma unroll
      for (int kc = 0; kc < 2; kc++) {
        bf16x8 bk = *(const bf16x8*)&Ks[cur][(n * 16 + l15) * 64 + (((kc * 4 + g) ^ rsw) << 3)];
        accS[n] = __builtin_amdgcn_mfma_f32_16x16x32_bf16(aq[kc], bk, accS[n], 0, 0, 0);
      }
    }
    __builtin_amdgcn_s_setprio(0);

    // causal mask (diag tile only) + lane-partial row maxima
    float tmaxp[4];
    #pragma unroll
    for (int j = 0; j < 4; j++) tmaxp[j] = -1e30f;
    const int qbase = q0 + w * 16 + g * 4;
    if (kt == qt) {    // diagonal tile (block-uniform branch)
      #pragma unroll
      for (int n = 0; n < 4; n++) {
        int key = kt * 64 + n * 16 + l15;
        #pragma unroll
        for (int j = 0; j < 4; j++) {
          float s = accS[n][j];
          if (key > qbase + j) s = -1e30f;
          accS[n][j] = s;
          tmaxp[j] = fmaxf(tmaxp[j], s);
        }
      }
    } else {
      #pragma unroll
      for (int n = 0; n < 4; n++)
        #pragma unroll
        for (int j = 0; j < 4; j++)
          tmaxp[j] = fmaxf(tmaxp[j], accS[n][j]);
    }

    // T13 defer-max: rescale only when some row's partial max exceeds m2+8
    float dmax = fmaxf(fmaxf(tmaxp[0] - m2[0], tmaxp[1] - m2[1]),
                       fmaxf(tmaxp[2] - m2[2], tmaxp[3] - m2[3]));
    if (!__all(dmax <= 8.0f)) {
      #pragma unroll
      for (int j = 0; j < 4; j++) {
        float t = tmaxp[j];
        #pragma unroll
        for (int off = 1; off < 16; off <<= 1)
          t = fmaxf(t, __shfl_xor(t, off));
        float mnew = fmaxf(m2[j], t);
        float al = exp2f(m2[j] - mnew);
        m2[j] = mnew;
        accL[j] *= al;
        #pragma unroll
        for (int n2 = 0; n2 < 4; n2++) accO[n2][j] *= al;
      }
    }

    // p = 2^(s - m2); slot-permuted pack: lane's 4 values per row are contiguous
    // (slot 4*l15+n holds key n*16+l15) -> one ds_write_b64 per row j.
    #pragma unroll
    for (int j = 0; j < 4; j++) {
      const int row = g * 4 + j;
      union { float f; unsigned u; } c0, c1, c2, c3;
      c0.f = exp2f(accS[0][j] - m2[j]);
      c1.f = exp2f(accS[1][j] - m2[j]);
      c2.f = exp2f(accS[2][j] - m2[j]);
      c3.f = exp2f(accS[3][j] - m2[j]);
      int2 pk;
      pk.x = (int)((c0.u >> 16) | (c1.u & 0xFFFF0000u));   // slots 4*l15+0,+1
      pk.y = (int)((c2.u >> 16) | (c3.u & 0xFFFF0000u));   // slots 4*l15+2,+3
      const int c8 = l15 ^ ((row & 7) << 1);               // 8B-chunk swizzle
      *(int2*)&PsW[row * 64 + (c8 << 2)] = pk;
    }

    __builtin_amdgcn_s_setprio(1);
    #pragma unroll
    for (int kc = 0; kc < 2; kc++) {
      bf16x8 pa = *(const bf16x8*)&PsW[l15 * 64 + (((kc * 4 + g) ^ rsw) << 3)];
      #pragma unroll
      for (int n2 = 0; n2 < 4; n2++) {
        bf16x8 vb = *(const bf16x8*)&Vs[cur][(n2 * 16 + l15) * 64 + (((kc * 4 + g) ^ rsw) << 3)];
        accO[n2] = __builtin_amdgcn_mfma_f32_16x16x32_bf16(pa, vb, accO[n2], 0, 0, 0);
      }
      accL = __builtin_amdgcn_mfma_f32_16x16x32_bf16(pa, vones, accL, 0, 0, 0);
    }
    __builtin_amdgcn_s_setprio(0);

    // barrier publishes the prefetched buffer (drains DMA vmcnt) and protects Ps
    __syncthreads();
  }

  // normalize (accL[j] = rowsum in every lane), dump Y tile into wave-private
  // PsW, then 2 coalesced bf16x8 stores per thread (no barrier needed).
  float inv[4];
  #pragma unroll
  for (int j = 0; j < 4; j++) inv[j] = 1.0f / accL[j];
  #pragma unroll
  for (int n2 = 0; n2 < 4; n2++) {
    #pragma unroll
    for (int j = 0; j < 4; j++) {
      float v = accO[n2][j] * inv[j];
      PsW[(g * 4 + j) * 64 + n2 * 16 + l15] = f2b(v);
    }
  }
  const int orow = b * TT + q0 + w * 16;
  #pragma unroll
  for (int i = 0; i < 2; i++) {
    int unit = lane + 64 * i;                 // 0..127: 16 rows x 8 chunks
    int row = unit >> 3, ch = unit & 7;
    bf16x8 vv = *(const bf16x8*)&PsW[row * 64 + ch * 8];
    *(bf16x8*)(Y + (size_t)(orow + row) * DM + h * 64 + ch * 8) = vv;
  }
}

extern "C" void kernel_launch(void* const* d_in, const int* in_sizes, int n_in,
                              void* d_out, int out_size, void* d_ws, size_t ws_size,
                              hipStream_t stream) {
  const float* x  = (const float*)d_in[0];
  const float* Wq = (const float*)d_in[1];
  const float* Wk = (const float*)d_in[2];
  const float* Wv = (const float*)d_in[3];
  const float* Wo = (const float*)d_in[4];
  float* out = (float*)d_out;

  char* ws = (char*)d_ws;
  size_t off = 0;
  auto alloc = [&](size_t bytes) {
    char* p = ws + off;
    off += (bytes + 255) & ~(size_t)255;
    return p;
  };
  short* xb    = (short*)alloc((size_t)NTOK * DM * 2);    // also reused as Y
  short* WqkvT = (short*)alloc((size_t)DQKV * DM * 2);    // [3072][1024]
  short* WoT   = (short*)alloc((size_t)DM * DM * 2);
  short* Qkv   = (short*)alloc((size_t)NTOK * DQKV * 2);  // [4096][3072]
  short* Vt    = (short*)alloc((size_t)NTOK * DM * 2);    // [32][64][2048]
  short* Yb    = xb;   // x dead after QKV GEMM; reuse region for Y
  if (off > ws_size) return;   // workspace too small -> loud failure

  k_convert<<<(NTOK * DM) / (256 * 8), 256, 0, stream>>>(x, xb, NTOK * DM);
  k_transpose_w4<<<dim3(DM / 64, DM / 64, 4), 256, 0, stream>>>(Wq, Wk, Wv, Wo, WqkvT, WoT);

  // fused QKV GEMM; Q cols pre-scaled by 0.125*log2e (softmax in log2 domain).
  // BN=64: 48KB LDS -> 3 blocks/CU (was 2 at BN=128) for the latency-bound loop.
  const float QSC = 0.125f * 1.44269504088896f;
  k_gemm_lds<1, 64><<<dim3((DQKV / 64) * (NTOK / 128)), 256, 0, stream>>>(xb, WqkvT, Qkv, NTOK, DQKV, DM, DM, QSC);

  k_transpose_v<<<dim3(TT / 64, BB * NH), 256, 0, stream>>>(Qkv + 2048, Vt);
  k_attn<<<dim3(1024), 256, 0, stream>>>(Qkv, Vt, Yb);

  // out projection: [4096][1024] x [1024][1024]^T -> fp32 out (128x64 tiles, 1D grid)
  k_gemm_lds<0, 64><<<dim3((DM / 64) * (NTOK / 128)), 256, 0, stream>>>(Yb, WoT, out, NTOK, DM, DM, 0, 1.0f);
}